// Round 2
// baseline (428.189 us; speedup 1.0000x reference)
//
#include <hip/hip_runtime.h>

#define BB   16
#define CCH  256
#define HH   96
#define WW   96
#define PHD  9
#define PWD  9
#define RAD  4
#define TH   8
#define TW   32
#define CC   8                 // channels per LDS chunk
#define NCHUNK (CCH / CC)      // 32
#define S2H  (TH + 2 * RAD)    // 16
#define S2W  (TW + 2 * RAD)    // 40
#define NTHREADS 576           // 9 waves: wave g handles dh = g-4
#define S2ELEMS (CC * S2H * S2W)   // 5120
#define S1ELEMS (CC * TH * TW)     // 2048 floats = 512 float4

__global__ __launch_bounds__(NTHREADS)
void corr_kernel(const float* __restrict__ in1,
                 const float* __restrict__ in2,
                 float* __restrict__ out) {
    __shared__ float s1[S1ELEMS];   // [c][row][col] linear
    __shared__ float s2[S2ELEMS];   // [c][r][col]  linear, row stride 40

    const int tid = threadIdx.x;
    const int w0  = blockIdx.x * TW;
    const int h0  = blockIdx.y * TH;
    const int b   = blockIdx.z;

    const float* p1 = in1 + (size_t)b * CCH * HH * WW;
    const float* p2 = in2 + (size_t)b * CCH * HH * WW;

    // ---- precompute staging descriptors (reused every chunk) ----
    // s1: one float4 per thread for tid < 512
    int g1ofs = 0;
    {
        int ch = tid >> 6, row = (tid >> 3) & 7, f4 = tid & 7;
        g1ofs = ch * (HH * WW) + (h0 + row) * WW + w0 + f4 * 4;
    }
    // s2: up to 9 scalar elems per thread; validity folded into offset sign
    int gofs[9];
    #pragma unroll
    for (int k = 0; k < 9; ++k) {
        int i = tid + k * NTHREADS;
        if (i < S2ELEMS) {
            int ch   = i / (S2H * S2W);
            int rem  = i - ch * (S2H * S2W);
            int r    = rem / S2W;
            int col  = rem - r * S2W;
            int grow = h0 - RAD + r;
            int gcol = w0 - RAD + col;
            bool valid = ((unsigned)grow < HH) && ((unsigned)gcol < WW);
            gofs[k] = valid ? (ch * (HH * WW) + grow * WW + gcol) : -1;
        } else {
            gofs[k] = -1;
        }
    }

    // ---- prefetch chunk 0 into registers ----
    float4 r1 = make_float4(0.f, 0.f, 0.f, 0.f);
    float  r2[9];
    if (tid < 512) r1 = *(const float4*)(p1 + g1ofs);
    #pragma unroll
    for (int k = 0; k < 9; ++k)
        r2[k] = (gofs[k] >= 0) ? p2[gofs[k]] : 0.f;

    const int lane = tid & 63;
    const int g    = tid >> 6;     // dh index (= ph) 0..8
    const int ly   = lane >> 3;    // tile row 0..7
    const int lx   = lane & 7;     // tile col group (4 floats each)

    float acc[PWD][4];
    #pragma unroll
    for (int dw = 0; dw < PWD; ++dw)
        #pragma unroll
        for (int r = 0; r < 4; ++r) acc[dw][r] = 0.f;

    const int s1_ro = (ly * 8 + lx) * 4;          // within-channel float offset
    const int s2_ro = (ly + g) * S2W + lx * 4;    // within-channel float offset

    for (int t = 0; t < NCHUNK; ++t) {
        __syncthreads();   // previous compute finished reading LDS
        if (tid < 512) *(float4*)(s1 + tid * 4) = r1;
        #pragma unroll
        for (int k = 0; k < 9; ++k) {
            int i = tid + k * NTHREADS;
            if (i < S2ELEMS) s2[i] = r2[k];
        }
        __syncthreads();   // LDS tiles ready

        // prefetch next chunk (latency hides under compute below)
        if (t + 1 < NCHUNK) {
            const float* q1 = p1 + (size_t)(t + 1) * CC * HH * WW;
            const float* q2 = p2 + (size_t)(t + 1) * CC * HH * WW;
            if (tid < 512) r1 = *(const float4*)(q1 + g1ofs);
            #pragma unroll
            for (int k = 0; k < 9; ++k)
                r2[k] = (gofs[k] >= 0) ? q2[gofs[k]] : 0.f;
        }

        // compute: 8 channels x (4 ds_read_b128 + 36 FMA)
        #pragma unroll
        for (int c = 0; c < CC; ++c) {
            float4 a4 = *(const float4*)(s1 + c * (TH * TW) + s1_ro);
            const float* brow = s2 + c * (S2H * S2W) + s2_ro;
            float4 b0 = *(const float4*)(brow);
            float4 b1 = *(const float4*)(brow + 4);
            float4 b2 = *(const float4*)(brow + 8);
            float av[4] = {a4.x, a4.y, a4.z, a4.w};
            float bb[12] = {b0.x, b0.y, b0.z, b0.w,
                            b1.x, b1.y, b1.z, b1.w,
                            b2.x, b2.y, b2.z, b2.w};
            #pragma unroll
            for (int dw = 0; dw < PWD; ++dw)
                #pragma unroll
                for (int r = 0; r < 4; ++r)
                    acc[dw][r] += av[r] * bb[dw + r];
        }
    }

    // ---- store: 9 float4 per thread, ph = g, pw = dw ----
    float* po = out + (size_t)((b * PHD + g) * PWD) * (HH * WW);
    #pragma unroll
    for (int dw = 0; dw < PWD; ++dw) {
        float4 v = make_float4(acc[dw][0], acc[dw][1], acc[dw][2], acc[dw][3]);
        *(float4*)(po + (size_t)dw * HH * WW + (h0 + ly) * WW + w0 + lx * 4) = v;
    }
}

extern "C" void kernel_launch(void* const* d_in, const int* in_sizes, int n_in,
                              void* d_out, int out_size, void* d_ws, size_t ws_size,
                              hipStream_t stream) {
    const float* in1 = (const float*)d_in[0];
    const float* in2 = (const float*)d_in[1];
    float* out = (float*)d_out;
    dim3 grid(WW / TW, HH / TH, BB);   // 3 x 12 x 16 = 576 blocks
    corr_kernel<<<grid, NTHREADS, 0, stream>>>(in1, in2, out);
}